// Round 6
// baseline (239.027 us; speedup 1.0000x reference)
//
#include <hip/hip_runtime.h>
#include <math.h>

#define C 128  // IN_C == OUT_C == 128

typedef _Float16 f16x8 __attribute__((ext_vector_type(8)));
typedef _Float16 half2_t __attribute__((ext_vector_type(2)));
typedef __attribute__((ext_vector_type(4))) float f32x4;

static __device__ __forceinline__ unsigned int pkh2(float lo, float hi) {
    unsigned short l = __builtin_bit_cast(unsigned short, (_Float16)lo);
    unsigned short h = __builtin_bit_cast(unsigned short, (_Float16)hi);
    return ((unsigned int)h << 16) | l;
}
static __device__ __forceinline__ float h2f_lo(unsigned int u) {
    return (float)__builtin_bit_cast(_Float16, (unsigned short)(u & 0xFFFFu));
}
static __device__ __forceinline__ float h2f_hi(unsigned int u) {
    return (float)__builtin_bit_cast(_Float16, (unsigned short)(u >> 16));
}
static __device__ __forceinline__ float dot2acc(unsigned int a, unsigned int b, float c) {
#if __has_builtin(__builtin_amdgcn_fdot2)
    return __builtin_amdgcn_fdot2(__builtin_bit_cast(half2_t, a),
                                  __builtin_bit_cast(half2_t, b), c, false);
#else
    c = fmaf(h2f_lo(a), h2f_lo(b), c);
    return fmaf(h2f_hi(a), h2f_hi(b), c);
#endif
}

// ---------------------------------------------------------------------------
// K0: f32 -> packed f16 for emb (first totalA8*8 elems) and W (rest).
// One thread = 8 elems.
// ---------------------------------------------------------------------------
__global__ __launch_bounds__(256) void k_cast(const float* __restrict__ embf,
                                              unsigned int* __restrict__ embh,
                                              const float* __restrict__ Wf,
                                              unsigned int* __restrict__ Wh,
                                              int totalA8, int totalB8) {
    int i = blockIdx.x * 256 + threadIdx.x;
    const float* in;
    unsigned int* outp;
    if (i < totalA8) {
        in = embf; outp = embh;
    } else {
        i -= totalA8;
        if (i >= totalB8) return;
        in = Wf; outp = Wh;
    }
    const float4 a = ((const float4*)in)[i * 2];
    const float4 b = ((const float4*)in)[i * 2 + 1];
    uint4 o;
    o.x = pkh2(a.x, a.y); o.y = pkh2(a.z, a.w);
    o.z = pkh2(b.x, b.y); o.w = pkh2(b.z, b.w);
    ((uint4*)outp)[i] = o;
}

// ---------------------------------------------------------------------------
// K1: xl = x @ W^T via MFMA f16. Block = 4 waves, 64 rows (16/wave).
// x read as f32 and converted in-register; W pre-cast to f16.
// C/D: col = lane&15, row = (lane>>4)*4 + reg.
// ---------------------------------------------------------------------------
__global__ __launch_bounds__(256) void k_gemm(const float* __restrict__ x,
                                              const uint4* __restrict__ wb,
                                              unsigned short* __restrict__ xlh, int N) {
    const int lane = threadIdx.x & 63;
    const int wave = threadIdx.x >> 6;
    const int row0 = blockIdx.x * 64 + wave * 16;
    const int r = lane & 15, kg = lane >> 4;

    int arow = row0 + r;
    if (arow >= N) arow = N - 1;          // clamp (stores are guarded)
    const float* xrow = x + (size_t)arow * C;
    f16x8 A[4];
#pragma unroll
    for (int kb = 0; kb < 4; ++kb) {
        const float4 p0 = ((const float4*)(xrow + kb * 32 + kg * 8))[0];
        const float4 p1 = ((const float4*)(xrow + kb * 32 + kg * 8))[1];
        f16x8 a;
        a[0] = (_Float16)p0.x; a[1] = (_Float16)p0.y;
        a[2] = (_Float16)p0.z; a[3] = (_Float16)p0.w;
        a[4] = (_Float16)p1.x; a[5] = (_Float16)p1.y;
        a[6] = (_Float16)p1.z; a[7] = (_Float16)p1.w;
        A[kb] = a;
    }

#pragma unroll
    for (int nt = 0; nt < 8; ++nt) {
        const uint4* wrow = wb + (size_t)(nt * 16 + r) * 16;
        f32x4 acc = {0.0f, 0.0f, 0.0f, 0.0f};
#pragma unroll
        for (int kb = 0; kb < 4; ++kb) {
            f16x8 B = __builtin_bit_cast(f16x8, wrow[kb * 4 + kg]);
            acc = __builtin_amdgcn_mfma_f32_16x16x32_f16(A[kb], B, acc, 0, 0, 0);
        }
        const int orow = row0 + kg * 4;
        const int ocol = nt * 16 + r;
#pragma unroll
        for (int i = 0; i < 4; ++i)
            if (orow + i < N)
                xlh[(size_t)(orow + i) * C + ocol] =
                    __builtin_bit_cast(unsigned short, (_Float16)acc[i]);
    }
}

// ---------------------------------------------------------------------------
// K3: CSR-by-dst build: histogram -> scan (2 kernels) -> scatter
// ---------------------------------------------------------------------------
__global__ void k_hist(const int* __restrict__ eidx, int* __restrict__ counts, int E) {
    int e = blockIdx.x * blockDim.x + threadIdx.x;
    if (e < E) atomicAdd(&counts[eidx[E + e]], 1);
}

__global__ __launch_bounds__(256) void k_scanA(const int* __restrict__ counts,
                                               int* __restrict__ offs,
                                               int* __restrict__ bsums, int N) {
    __shared__ int ts[256];
    const int t = threadIdx.x;
    const int base = blockIdx.x * 1024 + t * 4;
    int v[4];
    int s = 0;
#pragma unroll
    for (int j = 0; j < 4; ++j) {
        v[j] = (base + j < N) ? counts[base + j] : 0;
        s += v[j];
    }
    ts[t] = s;
    __syncthreads();
    for (int o = 1; o < 256; o <<= 1) {
        int u = (t >= o) ? ts[t - o] : 0;
        __syncthreads();
        ts[t] += u;
        __syncthreads();
    }
    int pref = (t == 0) ? 0 : ts[t - 1];
    if (t == 255) bsums[blockIdx.x] = ts[255];
#pragma unroll
    for (int j = 0; j < 4; ++j) {
        if (base + j < N) offs[base + j] = pref;
        pref += v[j];
    }
}

// scanC: block b adds sum(bsums[0..b-1]) to its 1024 offs entries (wave-reduce
// of <=64 block sums), mirrors into cursor; block 0 writes offs[N] = total.
// Requires nScanBlocks <= 64.
__global__ __launch_bounds__(256) void k_scanC(int* __restrict__ offs,
                                               int* __restrict__ cursor,
                                               const int* __restrict__ bsums,
                                               int N, int nb) {
    const int t = threadIdx.x;
    const int lane = t & 63;
    const int b = blockIdx.x;
    int v = (lane < nb) ? bsums[lane] : 0;
    int vp = (lane < b) ? v : 0;
    int tot = v, pre = vp;
#pragma unroll
    for (int o = 32; o >= 1; o >>= 1) {
        tot += __shfl_xor(tot, o);
        pre += __shfl_xor(pre, o);
    }
    const int base = b * 1024 + t * 4;
#pragma unroll
    for (int j = 0; j < 4; ++j) {
        const int i = base + j;
        if (i < N) {
            int o2 = offs[i] + pre;
            offs[i] = o2;
            cursor[i] = o2;
        }
    }
    if (b == 0 && t == 0) offs[N] = tot;
}

__global__ void k_scatter(const int* __restrict__ eidx, int* __restrict__ cursor,
                          int* __restrict__ src_s, int E) {
    int e = blockIdx.x * blockDim.x + threadIdx.x;
    if (e >= E) return;
    int d = eidx[E + e];
    int pos = atomicAdd(&cursor[d], 1);
    src_s[pos] = eidx[e];
}

// ---------------------------------------------------------------------------
// K4: fused attention + online softmax + aggregation. One wave per node.
// 8 edges/iter: 8-lane group g computes edge (base+g)'s dot via 8 v_dot2
// (f16), alphas broadcast wave-wide, 8 xl-row gathers in flight.
// ---------------------------------------------------------------------------
__global__ __launch_bounds__(256) void k_agg(const unsigned int* __restrict__ xlh,
                                             const unsigned int* __restrict__ embh,
                                             const int* __restrict__ src_s,
                                             const int* __restrict__ offs,
                                             const float* __restrict__ bias,
                                             float* __restrict__ out, int N) {
    const int node = (int)((blockIdx.x * (size_t)blockDim.x + threadIdx.x) >> 6);
    const int lane = threadIdx.x & 63;
    if (node >= N) return;
    const int g = lane >> 3;        // edge slot 0..7
    const int sl = lane & 7;        // sub-lane within 8-group
    const int s0 = offs[node], s1 = offs[node + 1];

    // emb[node]: 16 f16 per lane (2 uint4) in 8-lane layout
    const uint4* erow = (const uint4*)(embh + (size_t)node * (C / 2));
    const uint4 e0 = erow[sl * 2], e1 = erow[sl * 2 + 1];

    // self-loop logit = ||emb[node]||^2 (8-lane reduce; same in every group)
    float p = 0.0f;
    p = dot2acc(e0.x, e0.x, p); p = dot2acc(e0.y, e0.y, p);
    p = dot2acc(e0.z, e0.z, p); p = dot2acc(e0.w, e0.w, p);
    p = dot2acc(e1.x, e1.x, p); p = dot2acc(e1.y, e1.y, p);
    p = dot2acc(e1.z, e1.z, p); p = dot2acc(e1.w, e1.w, p);
#pragma unroll
    for (int o = 4; o >= 1; o >>= 1) p += __shfl_xor(p, o);

    float m = p;        // running max (self included)
    float d = 1.0f;     // exp(self - m) = 1
    const unsigned int xw = xlh[(size_t)node * (C / 2) + lane];
    float2 acc = {h2f_lo(xw), h2f_hi(xw)};

    for (int base = s0; base < s1; base += 8) {
        int mys = -1;
        if (lane < 8 && base + lane < s1) mys = src_s[base + lane];
        const int sg = __shfl(mys, g);
        const int sa = (sg >= 0) ? sg : node;

        // 8-lane dot: alpha_g = emb[node] . emb[src_g]
        const uint4* vrow = (const uint4*)(embh + (size_t)sa * (C / 2));
        const uint4 v0 = vrow[sl * 2], v1 = vrow[sl * 2 + 1];
        float a = 0.0f;
        a = dot2acc(e0.x, v0.x, a); a = dot2acc(e0.y, v0.y, a);
        a = dot2acc(e0.z, v0.z, a); a = dot2acc(e0.w, v0.w, a);
        a = dot2acc(e1.x, v1.x, a); a = dot2acc(e1.y, v1.y, a);
        a = dot2acc(e1.z, v1.z, a); a = dot2acc(e1.w, v1.w, a);
#pragma unroll
        for (int o = 4; o >= 1; o >>= 1) a += __shfl_xor(a, o);
        if (sg < 0) a = -INFINITY;

        // broadcast 8 alphas + srcs wave-wide
        float ag[8]; int bg[8];
#pragma unroll
        for (int j = 0; j < 8; ++j) {
            ag[j] = __shfl(a, j * 8);
            bg[j] = __shfl(mys, j);
        }
        const float amax = fmaxf(fmaxf(fmaxf(ag[0], ag[1]), fmaxf(ag[2], ag[3])),
                                 fmaxf(fmaxf(ag[4], ag[5]), fmaxf(ag[6], ag[7])));
        if (amax > m) {                 // wave-uniform, rare
            const float cs = __expf(m - amax);
            d *= cs; acc.x *= cs; acc.y *= cs;
            m = amax;
        }
        float w[8]; unsigned int u[8];
#pragma unroll
        for (int j = 0; j < 8; ++j) {
            w[j] = __expf(ag[j] - m);
            u[j] = xlh[(size_t)(bg[j] < 0 ? node : bg[j]) * (C / 2) + lane];
        }
#pragma unroll
        for (int j = 0; j < 8; ++j) {
            d += w[j];
            acc.x = fmaf(w[j], h2f_lo(u[j]), acc.x);
            acc.y = fmaf(w[j], h2f_hi(u[j]), acc.y);
        }
    }

    const float inv = 1.0f / (d + 1e-16f);
    const int c = lane * 2;
    float2 o2;
    o2.x = fmaf(acc.x, inv, bias[c]);
    o2.y = fmaf(acc.y, inv, bias[c + 1]);
    ((float2*)(out + (size_t)node * C))[lane] = o2;
}

// ---------------------------------------------------------------------------
// K5: BN stats — grid-stride float4; fixed channel quad per thread.
// ---------------------------------------------------------------------------
__global__ __launch_bounds__(256) void k_bnstats(const float* __restrict__ out,
                                                 float* __restrict__ ssum,
                                                 float* __restrict__ ssq, int N) {
    const int tid = threadIdx.x;
    const int total4 = N * (C / 4);
    const int stride = gridDim.x * 256;          // multiple of 32
    float4 s4 = {0, 0, 0, 0}, q4 = {0, 0, 0, 0};
    for (int i = blockIdx.x * 256 + tid; i < total4; i += stride) {
        float4 v = ((const float4*)out)[i];
        s4.x += v.x; s4.y += v.y; s4.z += v.z; s4.w += v.w;
        q4.x = fmaf(v.x, v.x, q4.x); q4.y = fmaf(v.y, v.y, q4.y);
        q4.z = fmaf(v.z, v.z, q4.z); q4.w = fmaf(v.w, v.w, q4.w);
    }
    __shared__ float4 lsum[256];
    __shared__ float4 lsq[256];
    lsum[tid] = s4; lsq[tid] = q4;
    __syncthreads();
    if (tid < 32) {
        float4 S = lsum[tid], Q = lsq[tid];
#pragma unroll
        for (int j = 1; j < 8; ++j) {
            float4 a = lsum[tid + 32 * j], b = lsq[tid + 32 * j];
            S.x += a.x; S.y += a.y; S.z += a.z; S.w += a.w;
            Q.x += b.x; Q.y += b.y; Q.z += b.z; Q.w += b.w;
        }
        const int c = tid * 4;
        atomicAdd(&ssum[c], S.x);     atomicAdd(&ssum[c + 1], S.y);
        atomicAdd(&ssum[c + 2], S.z); atomicAdd(&ssum[c + 3], S.w);
        atomicAdd(&ssq[c], Q.x);      atomicAdd(&ssq[c + 1], Q.y);
        atomicAdd(&ssq[c + 2], Q.z);  atomicAdd(&ssq[c + 3], Q.w);
    }
}

// ---------------------------------------------------------------------------
// K6: in-place BN apply (training-mode batch stats, biased var) + ReLU
// ---------------------------------------------------------------------------
__global__ __launch_bounds__(256) void k_bnapply(float* __restrict__ out,
                                                 const float* __restrict__ ssum,
                                                 const float* __restrict__ ssq,
                                                 const float* __restrict__ gamma,
                                                 const float* __restrict__ beta,
                                                 int N) {
    const int idx = blockIdx.x * blockDim.x + threadIdx.x;   // float4 index
    const int total = N * (C / 4);
    if (idx >= total) return;
    const int c = (idx * 4) & 127;
    float4 v = ((const float4*)out)[idx];
    const float invN = 1.0f / (float)N;
    float r[4] = {v.x, v.y, v.z, v.w};
#pragma unroll
    for (int j = 0; j < 4; ++j) {
        float mu = ssum[c + j] * invN;
        float var = fmaf(-mu, mu, ssq[c + j] * invN);
        var = fmaxf(var, 0.0f);
        float sc = gamma[c + j] / sqrtf(var + 1e-5f);
        float val = fmaf(r[j] - mu, sc, beta[c + j]);
        r[j] = fmaxf(val, 0.0f);
    }
    float4 o = {r[0], r[1], r[2], r[3]};
    ((float4*)out)[idx] = o;
}

// ---------------------------------------------------------------------------
extern "C" void kernel_launch(void* const* d_in, const int* in_sizes, int n_in,
                              void* d_out, int out_size, void* d_ws, size_t ws_size,
                              hipStream_t stream) {
    const float* x     = (const float*)d_in[0];
    const int*   eidx  = (const int*)d_in[1];   // [2][E]
    const float* emb   = (const float*)d_in[2];
    const float* W     = (const float*)d_in[3];
    const float* bias  = (const float*)d_in[4];
    const float* gamma = (const float*)d_in[5];
    const float* beta  = (const float*)d_in[6];
    const int N = in_sizes[0] / C;
    const int E = in_sizes[1] / 2;
    float* out = (float*)d_out;

    char* ws = (char*)d_ws;
    size_t off = 0;
    auto alloc = [&](size_t bytes) -> void* {
        void* p = ws + off;
        off = (off + bytes + 255) & ~(size_t)255;
        return p;
    };
    unsigned short* xlh  = (unsigned short*)alloc((size_t)N * C * 2);
    unsigned int*   embh = (unsigned int*)  alloc((size_t)N * C * 2);
    unsigned int*   wh   = (unsigned int*)  alloc((size_t)C * C * 2);
    int*   src_s   = (int*)  alloc((size_t)E * 4);
    int*   cursor  = (int*)  alloc((size_t)N * 4);
    int*   offs    = (int*)  alloc((size_t)(N + 1) * 4);
    int*   bsums   = (int*)  alloc(256 * 4);
    // contiguous zero-init region: counts + ssum + ssq
    char*  zbase   = (char*)alloc(0);
    int*   counts  = (int*)  alloc((size_t)N * 4);
    float* ssum    = (float*)alloc(C * 4);
    float* ssq     = (float*)alloc(C * 4);
    size_t zbytes  = (char*)ws + off - zbase;

    const int nScanBlocks = (N + 1023) / 1024;   // 49 for N=50000 (must be <=64)
    const int embTot8 = N * (C / 8);
    const int wTot8   = C * (C / 8);

    hipMemsetAsync(zbase, 0, zbytes, stream);

    k_cast   <<<(embTot8 + wTot8 + 255) / 256, 256, 0, stream>>>(
                 emb, embh, W, wh, embTot8, wTot8);
    k_gemm   <<<(N + 63) / 64,    256, 0, stream>>>(x, (const uint4*)wh, xlh, N);
    k_hist   <<<(E + 255) / 256,  256, 0, stream>>>(eidx, counts, E);
    k_scanA  <<<nScanBlocks,      256, 0, stream>>>(counts, offs, bsums, N);
    k_scanC  <<<nScanBlocks,      256, 0, stream>>>(offs, cursor, bsums, N, nScanBlocks);
    k_scatter<<<(E + 255) / 256,  256, 0, stream>>>(eidx, cursor, src_s, E);
    k_agg    <<<(int)(((size_t)N * 64 + 255) / 256), 256, 0, stream>>>(
                 (const unsigned int*)xlh, embh, src_s, offs, bias, out, N);
    k_bnstats<<<256,              256, 0, stream>>>(out, ssum, ssq, N);
    k_bnapply<<<(N * (C / 4) + 255) / 256, 256, 0, stream>>>(out, ssum, ssq, gamma, beta, N);
}

// Round 7
// 178.405 us; speedup vs baseline: 1.3398x; 1.3398x over previous
//
#include <hip/hip_runtime.h>
#include <math.h>

#define C 128  // IN_C == OUT_C == 128

typedef _Float16 f16x8 __attribute__((ext_vector_type(8)));
typedef _Float16 half2_t __attribute__((ext_vector_type(2)));
typedef __attribute__((ext_vector_type(4))) float f32x4;

static __device__ __forceinline__ unsigned int pkh2(float lo, float hi) {
    unsigned short l = __builtin_bit_cast(unsigned short, (_Float16)lo);
    unsigned short h = __builtin_bit_cast(unsigned short, (_Float16)hi);
    return ((unsigned int)h << 16) | l;
}
static __device__ __forceinline__ float h2f_lo(unsigned int u) {
    return (float)__builtin_bit_cast(_Float16, (unsigned short)(u & 0xFFFFu));
}
static __device__ __forceinline__ float h2f_hi(unsigned int u) {
    return (float)__builtin_bit_cast(_Float16, (unsigned short)(u >> 16));
}
static __device__ __forceinline__ float dot2acc(unsigned int a, unsigned int b, float c) {
#if __has_builtin(__builtin_amdgcn_fdot2)
    return __builtin_amdgcn_fdot2(__builtin_bit_cast(half2_t, a),
                                  __builtin_bit_cast(half2_t, b), c, false);
#else
    c = fmaf(h2f_lo(a), h2f_lo(b), c);
    return fmaf(h2f_hi(a), h2f_hi(b), c);
#endif
}

// ---------------------------------------------------------------------------
// K0: f32 -> packed f16 for emb and W. One thread = 8 elems.
// ---------------------------------------------------------------------------
__global__ __launch_bounds__(256) void k_cast(const float* __restrict__ embf,
                                              unsigned int* __restrict__ embh,
                                              const float* __restrict__ Wf,
                                              unsigned int* __restrict__ Wh,
                                              int totalA8, int totalB8) {
    int i = blockIdx.x * 256 + threadIdx.x;
    const float* in;
    unsigned int* outp;
    if (i < totalA8) {
        in = embf; outp = embh;
    } else {
        i -= totalA8;
        if (i >= totalB8) return;
        in = Wf; outp = Wh;
    }
    const float4 a = ((const float4*)in)[i * 2];
    const float4 b = ((const float4*)in)[i * 2 + 1];
    uint4 o;
    o.x = pkh2(a.x, a.y); o.y = pkh2(a.z, a.w);
    o.z = pkh2(b.x, b.y); o.w = pkh2(b.z, b.w);
    ((uint4*)outp)[i] = o;
}

// ---------------------------------------------------------------------------
// K1: xl = x @ W^T via MFMA f16. Block = 4 waves, 64 rows (16/wave).
// ---------------------------------------------------------------------------
__global__ __launch_bounds__(256) void k_gemm(const float* __restrict__ x,
                                              const uint4* __restrict__ wb,
                                              unsigned short* __restrict__ xlh, int N) {
    const int lane = threadIdx.x & 63;
    const int wave = threadIdx.x >> 6;
    const int row0 = blockIdx.x * 64 + wave * 16;
    const int r = lane & 15, kg = lane >> 4;

    int arow = row0 + r;
    if (arow >= N) arow = N - 1;          // clamp (stores are guarded)
    const float* xrow = x + (size_t)arow * C;
    f16x8 A[4];
#pragma unroll
    for (int kb = 0; kb < 4; ++kb) {
        const float4 p0 = ((const float4*)(xrow + kb * 32 + kg * 8))[0];
        const float4 p1 = ((const float4*)(xrow + kb * 32 + kg * 8))[1];
        f16x8 a;
        a[0] = (_Float16)p0.x; a[1] = (_Float16)p0.y;
        a[2] = (_Float16)p0.z; a[3] = (_Float16)p0.w;
        a[4] = (_Float16)p1.x; a[5] = (_Float16)p1.y;
        a[6] = (_Float16)p1.z; a[7] = (_Float16)p1.w;
        A[kb] = a;
    }

#pragma unroll
    for (int nt = 0; nt < 8; ++nt) {
        const uint4* wrow = wb + (size_t)(nt * 16 + r) * 16;
        f32x4 acc = {0.0f, 0.0f, 0.0f, 0.0f};
#pragma unroll
        for (int kb = 0; kb < 4; ++kb) {
            f16x8 B = __builtin_bit_cast(f16x8, wrow[kb * 4 + kg]);
            acc = __builtin_amdgcn_mfma_f32_16x16x32_f16(A[kb], B, acc, 0, 0, 0);
        }
        const int orow = row0 + kg * 4;
        const int ocol = nt * 16 + r;
#pragma unroll
        for (int i = 0; i < 4; ++i)
            if (orow + i < N)
                xlh[(size_t)(orow + i) * C + ocol] =
                    __builtin_bit_cast(unsigned short, (_Float16)acc[i]);
    }
}

// ---------------------------------------------------------------------------
// CSR build, bucket-sort style. Bin = dst>>8 (exactly 256 nodes per bin).
// ---------------------------------------------------------------------------
// K2a: per-bin edge counts (LDS-aggregated; 2048 edges per block)
__global__ __launch_bounds__(256) void k_binhist(const int* __restrict__ eidx,
                                                 int* __restrict__ binCounts, int E) {
    __shared__ int lh[256];
    const int t = threadIdx.x;
    lh[t] = 0;
    __syncthreads();
    const int base = blockIdx.x * 2048;
#pragma unroll
    for (int j = 0; j < 8; ++j) {
        const int e = base + j * 256 + t;
        if (e < E) atomicAdd(&lh[eidx[E + e] >> 8], 1);
    }
    __syncthreads();
    const int v = lh[t];
    if (v) atomicAdd(&binCounts[t], v);
}

// K2b: exclusive scan of bin counts (NB <= 255) -> binOffs[0..NB], binCursor
__global__ __launch_bounds__(256) void k_binscan(const int* __restrict__ binCounts,
                                                 int* __restrict__ binOffs,
                                                 int* __restrict__ binCursor, int NB) {
    __shared__ int ts[256];
    const int t = threadIdx.x;
    const int v = (t < NB) ? binCounts[t] : 0;
    ts[t] = v;
    __syncthreads();
    for (int o = 1; o < 256; o <<= 1) {
        int u = (t >= o) ? ts[t - o] : 0;
        __syncthreads();
        ts[t] += u;
        __syncthreads();
    }
    const int excl = ts[t] - v;
    if (t <= NB) binOffs[t] = excl;     // binOffs[NB] = E (thread NB has v=0)
    if (t < NB) binCursor[t] = excl;
}

// K2c: bin edges into bucket-contiguous (src,dst) records.
// Block handles 2048 edges: LDS-rank per bin, one global reservation per
// (block,bin), then grouped writes (~10 records/chunk contiguous).
__global__ __launch_bounds__(256) void k_bin(const int* __restrict__ eidx,
                                             int* __restrict__ binCursor,
                                             uint2* __restrict__ binned, int E) {
    __shared__ int lh[256];
    __shared__ int lb[256];
    const int t = threadIdx.x;
    lh[t] = 0;
    __syncthreads();
    const int base = blockIdx.x * 2048;
    int bj[8], rj[8], sj[8], dj[8];
#pragma unroll
    for (int j = 0; j < 8; ++j) {
        const int e = base + j * 256 + t;
        bj[j] = -1;
        if (e < E) {
            sj[j] = eidx[e];
            dj[j] = eidx[E + e];
            bj[j] = dj[j] >> 8;
            rj[j] = atomicAdd(&lh[bj[j]], 1);
        }
    }
    __syncthreads();
    const int c = lh[t];
    if (c) lb[t] = atomicAdd(&binCursor[t], c);
    __syncthreads();
#pragma unroll
    for (int j = 0; j < 8; ++j) {
        if (bj[j] >= 0) {
            uint2 rec;
            rec.x = (unsigned)sj[j];
            rec.y = (unsigned)dj[j];
            binned[lb[bj[j]] + rj[j]] = rec;
        }
    }
}

// K2d: one block per bin (owns nodes [b*256, b*256+256) exclusively).
// Builds per-node counts + offs via LDS scan (replaces hist/scanA/scanC),
// then places src ids with LDS cursors — zero global atomics, and all
// scattered writes land in the bin's ~16KB CSR window (L2-hot).
__global__ __launch_bounds__(256) void k_place(const uint2* __restrict__ binned,
                                               const int* __restrict__ binOffs,
                                               int* __restrict__ offs,
                                               int* __restrict__ src_s,
                                               int N, int E) {
    __shared__ int cnt[256];
    __shared__ int ts[256];
    __shared__ int cur[256];
    const int b = blockIdx.x;
    const int t = threadIdx.x;
    const int node0 = b * 256;
    const int r0 = binOffs[b], r1 = binOffs[b + 1];
    cnt[t] = 0;
    __syncthreads();
    for (int i = r0 + t; i < r1; i += 256)
        atomicAdd(&cnt[binned[i].y & 255], 1);
    __syncthreads();
    const int v = cnt[t];
    ts[t] = v;
    __syncthreads();
    for (int o = 1; o < 256; o <<= 1) {
        int u = (t >= o) ? ts[t - o] : 0;
        __syncthreads();
        ts[t] += u;
        __syncthreads();
    }
    const int excl = r0 + ts[t] - v;
    if (node0 + t < N) offs[node0 + t] = excl;
    cur[t] = excl;
    __syncthreads();
    for (int i = r0 + t; i < r1; i += 256) {
        const uint2 rec = binned[i];
        const int pos = atomicAdd(&cur[rec.y & 255], 1);
        src_s[pos] = (int)rec.x;
    }
    if (b == 0 && t == 0) offs[N] = E;
}

// ---------------------------------------------------------------------------
// K4: fused attention + online softmax + aggregation. One wave per node.
// 8 edges/iter, 8-lane dots via v_dot2 (f16), 8 xl gathers in flight.
// ---------------------------------------------------------------------------
__global__ __launch_bounds__(256) void k_agg(const unsigned int* __restrict__ xlh,
                                             const unsigned int* __restrict__ embh,
                                             const int* __restrict__ src_s,
                                             const int* __restrict__ offs,
                                             const float* __restrict__ bias,
                                             float* __restrict__ out, int N) {
    const int node = (int)((blockIdx.x * (size_t)blockDim.x + threadIdx.x) >> 6);
    const int lane = threadIdx.x & 63;
    if (node >= N) return;
    const int g = lane >> 3;        // edge slot 0..7
    const int sl = lane & 7;        // sub-lane within 8-group
    const int s0 = offs[node], s1 = offs[node + 1];

    const uint4* erow = (const uint4*)(embh + (size_t)node * (C / 2));
    const uint4 e0 = erow[sl * 2], e1 = erow[sl * 2 + 1];

    // self-loop logit = ||emb[node]||^2 (8-lane reduce; same in every group)
    float p = 0.0f;
    p = dot2acc(e0.x, e0.x, p); p = dot2acc(e0.y, e0.y, p);
    p = dot2acc(e0.z, e0.z, p); p = dot2acc(e0.w, e0.w, p);
    p = dot2acc(e1.x, e1.x, p); p = dot2acc(e1.y, e1.y, p);
    p = dot2acc(e1.z, e1.z, p); p = dot2acc(e1.w, e1.w, p);
#pragma unroll
    for (int o = 4; o >= 1; o >>= 1) p += __shfl_xor(p, o);

    float m = p;        // running max (self included)
    float d = 1.0f;     // exp(self - m) = 1
    const unsigned int xw = xlh[(size_t)node * (C / 2) + lane];
    float2 acc = {h2f_lo(xw), h2f_hi(xw)};

    for (int base = s0; base < s1; base += 8) {
        int mys = -1;
        if (lane < 8 && base + lane < s1) mys = src_s[base + lane];
        const int sg = __shfl(mys, g);
        const int sa = (sg >= 0) ? sg : node;

        const uint4* vrow = (const uint4*)(embh + (size_t)sa * (C / 2));
        const uint4 v0 = vrow[sl * 2], v1 = vrow[sl * 2 + 1];
        float a = 0.0f;
        a = dot2acc(e0.x, v0.x, a); a = dot2acc(e0.y, v0.y, a);
        a = dot2acc(e0.z, v0.z, a); a = dot2acc(e0.w, v0.w, a);
        a = dot2acc(e1.x, v1.x, a); a = dot2acc(e1.y, v1.y, a);
        a = dot2acc(e1.z, v1.z, a); a = dot2acc(e1.w, v1.w, a);
#pragma unroll
        for (int o = 4; o >= 1; o >>= 1) a += __shfl_xor(a, o);
        if (sg < 0) a = -INFINITY;

        float ag[8]; int bg[8];
#pragma unroll
        for (int j = 0; j < 8; ++j) {
            ag[j] = __shfl(a, j * 8);
            bg[j] = __shfl(mys, j);
        }
        const float amax = fmaxf(fmaxf(fmaxf(ag[0], ag[1]), fmaxf(ag[2], ag[3])),
                                 fmaxf(fmaxf(ag[4], ag[5]), fmaxf(ag[6], ag[7])));
        if (amax > m) {                 // wave-uniform, rare
            const float cs = __expf(m - amax);
            d *= cs; acc.x *= cs; acc.y *= cs;
            m = amax;
        }
        float w[8]; unsigned int u[8];
#pragma unroll
        for (int j = 0; j < 8; ++j) {
            w[j] = __expf(ag[j] - m);
            u[j] = xlh[(size_t)(bg[j] < 0 ? node : bg[j]) * (C / 2) + lane];
        }
#pragma unroll
        for (int j = 0; j < 8; ++j) {
            d += w[j];
            acc.x = fmaf(w[j], h2f_lo(u[j]), acc.x);
            acc.y = fmaf(w[j], h2f_hi(u[j]), acc.y);
        }
    }

    const float inv = 1.0f / (d + 1e-16f);
    const int c = lane * 2;
    float2 o2;
    o2.x = fmaf(acc.x, inv, bias[c]);
    o2.y = fmaf(acc.y, inv, bias[c + 1]);
    ((float2*)(out + (size_t)node * C))[lane] = o2;
}

// ---------------------------------------------------------------------------
// K5: BN stats — grid-stride float4; fixed channel quad per thread.
// ---------------------------------------------------------------------------
__global__ __launch_bounds__(256) void k_bnstats(const float* __restrict__ out,
                                                 float* __restrict__ ssum,
                                                 float* __restrict__ ssq, int N) {
    const int tid = threadIdx.x;
    const int total4 = N * (C / 4);
    const int stride = gridDim.x * 256;          // multiple of 32
    float4 s4 = {0, 0, 0, 0}, q4 = {0, 0, 0, 0};
    for (int i = blockIdx.x * 256 + tid; i < total4; i += stride) {
        float4 v = ((const float4*)out)[i];
        s4.x += v.x; s4.y += v.y; s4.z += v.z; s4.w += v.w;
        q4.x = fmaf(v.x, v.x, q4.x); q4.y = fmaf(v.y, v.y, q4.y);
        q4.z = fmaf(v.z, v.z, q4.z); q4.w = fmaf(v.w, v.w, q4.w);
    }
    __shared__ float4 lsum[256];
    __shared__ float4 lsq[256];
    lsum[tid] = s4; lsq[tid] = q4;
    __syncthreads();
    if (tid < 32) {
        float4 S = lsum[tid], Q = lsq[tid];
#pragma unroll
        for (int j = 1; j < 8; ++j) {
            float4 a = lsum[tid + 32 * j], b = lsq[tid + 32 * j];
            S.x += a.x; S.y += a.y; S.z += a.z; S.w += a.w;
            Q.x += b.x; Q.y += b.y; Q.z += b.z; Q.w += b.w;
        }
        const int c = tid * 4;
        atomicAdd(&ssum[c], S.x);     atomicAdd(&ssum[c + 1], S.y);
        atomicAdd(&ssum[c + 2], S.z); atomicAdd(&ssum[c + 3], S.w);
        atomicAdd(&ssq[c], Q.x);      atomicAdd(&ssq[c + 1], Q.y);
        atomicAdd(&ssq[c + 2], Q.z);  atomicAdd(&ssq[c + 3], Q.w);
    }
}

// ---------------------------------------------------------------------------
// K6: in-place BN apply (training-mode batch stats, biased var) + ReLU
// ---------------------------------------------------------------------------
__global__ __launch_bounds__(256) void k_bnapply(float* __restrict__ out,
                                                 const float* __restrict__ ssum,
                                                 const float* __restrict__ ssq,
                                                 const float* __restrict__ gamma,
                                                 const float* __restrict__ beta,
                                                 int N) {
    const int idx = blockIdx.x * blockDim.x + threadIdx.x;   // float4 index
    const int total = N * (C / 4);
    if (idx >= total) return;
    const int c = (idx * 4) & 127;
    float4 v = ((const float4*)out)[idx];
    const float invN = 1.0f / (float)N;
    float r[4] = {v.x, v.y, v.z, v.w};
#pragma unroll
    for (int j = 0; j < 4; ++j) {
        float mu = ssum[c + j] * invN;
        float var = fmaf(-mu, mu, ssq[c + j] * invN);
        var = fmaxf(var, 0.0f);
        float sc = gamma[c + j] / sqrtf(var + 1e-5f);
        float val = fmaf(r[j] - mu, sc, beta[c + j]);
        r[j] = fmaxf(val, 0.0f);
    }
    float4 o = {r[0], r[1], r[2], r[3]};
    ((float4*)out)[idx] = o;
}

// ---------------------------------------------------------------------------
extern "C" void kernel_launch(void* const* d_in, const int* in_sizes, int n_in,
                              void* d_out, int out_size, void* d_ws, size_t ws_size,
                              hipStream_t stream) {
    const float* x     = (const float*)d_in[0];
    const int*   eidx  = (const int*)d_in[1];   // [2][E]
    const float* emb   = (const float*)d_in[2];
    const float* W     = (const float*)d_in[3];
    const float* bias  = (const float*)d_in[4];
    const float* gamma = (const float*)d_in[5];
    const float* beta  = (const float*)d_in[6];
    const int N = in_sizes[0] / C;
    const int E = in_sizes[1] / 2;
    float* out = (float*)d_out;

    char* ws = (char*)d_ws;
    size_t off = 0;
    auto alloc = [&](size_t bytes) -> void* {
        void* p = ws + off;
        off = (off + bytes + 255) & ~(size_t)255;
        return p;
    };
    unsigned short* xlh  = (unsigned short*)alloc((size_t)N * C * 2);
    unsigned int*   embh = (unsigned int*)  alloc((size_t)N * C * 2);
    unsigned int*   wh   = (unsigned int*)  alloc((size_t)C * C * 2);
    int*   src_s    = (int*)  alloc((size_t)E * 4);
    uint2* binned   = (uint2*)alloc((size_t)E * 8);
    int*   offs     = (int*)  alloc((size_t)(N + 1) * 4);
    int*   binOffs  = (int*)  alloc(257 * 4);
    int*   binCur   = (int*)  alloc(256 * 4);
    // contiguous zero-init region: binCounts + ssum + ssq
    char*  zbase    = (char*)alloc(0);
    int*   binCounts= (int*)  alloc(256 * 4);
    float* ssum     = (float*)alloc(C * 4);
    float* ssq      = (float*)alloc(C * 4);
    size_t zbytes   = (char*)ws + off - zbase;

    const int NB = (N + 255) / 256;              // 196 bins (<= 255)
    const int nEdgeBlocks = (E + 2047) / 2048;   // 391
    const int embTot8 = N * (C / 8);
    const int wTot8   = C * (C / 8);

    hipMemsetAsync(zbase, 0, zbytes, stream);

    k_cast   <<<(embTot8 + wTot8 + 255) / 256, 256, 0, stream>>>(
                 emb, embh, W, wh, embTot8, wTot8);
    k_gemm   <<<(N + 63) / 64,   256, 0, stream>>>(x, (const uint4*)wh, xlh, N);
    k_binhist<<<nEdgeBlocks,     256, 0, stream>>>(eidx, binCounts, E);
    k_binscan<<<1,               256, 0, stream>>>(binCounts, binOffs, binCur, NB);
    k_bin    <<<nEdgeBlocks,     256, 0, stream>>>(eidx, binCur, binned, E);
    k_place  <<<NB,              256, 0, stream>>>(binned, binOffs, offs, src_s, N, E);
    k_agg    <<<(int)(((size_t)N * 64 + 255) / 256), 256, 0, stream>>>(
                 (const unsigned int*)xlh, embh, src_s, offs, bias, out, N);
    k_bnstats<<<256,             256, 0, stream>>>(out, ssum, ssq, N);
    k_bnapply<<<(N * (C / 4) + 255) / 256, 256, 0, stream>>>(out, ssum, ssq, gamma, beta, N);
}

// Round 8
// 158.476 us; speedup vs baseline: 1.5083x; 1.1258x over previous
//
#include <hip/hip_runtime.h>
#include <math.h>

#define C 128  // IN_C == OUT_C == 128

typedef _Float16 f16x8 __attribute__((ext_vector_type(8)));
typedef _Float16 half2_t __attribute__((ext_vector_type(2)));
typedef __attribute__((ext_vector_type(4))) float f32x4;

static __device__ __forceinline__ unsigned int pkh2(float lo, float hi) {
    unsigned short l = __builtin_bit_cast(unsigned short, (_Float16)lo);
    unsigned short h = __builtin_bit_cast(unsigned short, (_Float16)hi);
    return ((unsigned int)h << 16) | l;
}
static __device__ __forceinline__ float h2f_lo(unsigned int u) {
    return (float)__builtin_bit_cast(_Float16, (unsigned short)(u & 0xFFFFu));
}
static __device__ __forceinline__ float h2f_hi(unsigned int u) {
    return (float)__builtin_bit_cast(_Float16, (unsigned short)(u >> 16));
}
static __device__ __forceinline__ float dot2acc(unsigned int a, unsigned int b, float c) {
#if __has_builtin(__builtin_amdgcn_fdot2)
    return __builtin_amdgcn_fdot2(__builtin_bit_cast(half2_t, a),
                                  __builtin_bit_cast(half2_t, b), c, false);
#else
    c = fmaf(h2f_lo(a), h2f_lo(b), c);
    return fmaf(h2f_hi(a), h2f_hi(b), c);
#endif
}

// ---------------------------------------------------------------------------
// K0: f32 -> packed f16 for emb and W. One thread = 8 elems.
// ---------------------------------------------------------------------------
__global__ __launch_bounds__(256) void k_cast(const float* __restrict__ embf,
                                              unsigned int* __restrict__ embh,
                                              const float* __restrict__ Wf,
                                              unsigned int* __restrict__ Wh,
                                              int totalA8, int totalB8) {
    int i = blockIdx.x * 256 + threadIdx.x;
    const float* in;
    unsigned int* outp;
    if (i < totalA8) {
        in = embf; outp = embh;
    } else {
        i -= totalA8;
        if (i >= totalB8) return;
        in = Wf; outp = Wh;
    }
    const float4 a = ((const float4*)in)[i * 2];
    const float4 b = ((const float4*)in)[i * 2 + 1];
    uint4 o;
    o.x = pkh2(a.x, a.y); o.y = pkh2(a.z, a.w);
    o.z = pkh2(b.x, b.y); o.w = pkh2(b.z, b.w);
    ((uint4*)outp)[i] = o;
}

// ---------------------------------------------------------------------------
// K1: xl = x @ W^T via MFMA f16. Block = 4 waves, 64 rows (16/wave).
// ---------------------------------------------------------------------------
__global__ __launch_bounds__(256) void k_gemm(const float* __restrict__ x,
                                              const uint4* __restrict__ wb,
                                              unsigned short* __restrict__ xlh, int N) {
    const int lane = threadIdx.x & 63;
    const int wave = threadIdx.x >> 6;
    const int row0 = blockIdx.x * 64 + wave * 16;
    const int r = lane & 15, kg = lane >> 4;

    int arow = row0 + r;
    if (arow >= N) arow = N - 1;          // clamp (stores are guarded)
    const float* xrow = x + (size_t)arow * C;
    f16x8 A[4];
#pragma unroll
    for (int kb = 0; kb < 4; ++kb) {
        const float4 p0 = ((const float4*)(xrow + kb * 32 + kg * 8))[0];
        const float4 p1 = ((const float4*)(xrow + kb * 32 + kg * 8))[1];
        f16x8 a;
        a[0] = (_Float16)p0.x; a[1] = (_Float16)p0.y;
        a[2] = (_Float16)p0.z; a[3] = (_Float16)p0.w;
        a[4] = (_Float16)p1.x; a[5] = (_Float16)p1.y;
        a[6] = (_Float16)p1.z; a[7] = (_Float16)p1.w;
        A[kb] = a;
    }

#pragma unroll
    for (int nt = 0; nt < 8; ++nt) {
        const uint4* wrow = wb + (size_t)(nt * 16 + r) * 16;
        f32x4 acc = {0.0f, 0.0f, 0.0f, 0.0f};
#pragma unroll
        for (int kb = 0; kb < 4; ++kb) {
            f16x8 B = __builtin_bit_cast(f16x8, wrow[kb * 4 + kg]);
            acc = __builtin_amdgcn_mfma_f32_16x16x32_f16(A[kb], B, acc, 0, 0, 0);
        }
        const int orow = row0 + kg * 4;
        const int ocol = nt * 16 + r;
#pragma unroll
        for (int i = 0; i < 4; ++i)
            if (orow + i < N)
                xlh[(size_t)(orow + i) * C + ocol] =
                    __builtin_bit_cast(unsigned short, (_Float16)acc[i]);
    }
}

// ---------------------------------------------------------------------------
// CSR build, bucket-sort style. Bin = dst>>8 (exactly 256 nodes per bin).
// Record packed u32: [31:24] = dst&255, [23:0] = src  (needs N < 2^24).
// ---------------------------------------------------------------------------
__global__ __launch_bounds__(256) void k_binhist(const int* __restrict__ eidx,
                                                 int* __restrict__ binCounts, int E) {
    __shared__ int lh[256];
    const int t = threadIdx.x;
    lh[t] = 0;
    __syncthreads();
    const int base = blockIdx.x * 2048;
#pragma unroll
    for (int j = 0; j < 8; ++j) {
        const int e = base + j * 256 + t;
        if (e < E) atomicAdd(&lh[eidx[E + e] >> 8], 1);
    }
    __syncthreads();
    const int v = lh[t];
    if (v) atomicAdd(&binCounts[t], v);
}

__global__ __launch_bounds__(256) void k_binscan(const int* __restrict__ binCounts,
                                                 int* __restrict__ binOffs,
                                                 int* __restrict__ binCursor, int NB) {
    __shared__ int ts[256];
    const int t = threadIdx.x;
    const int v = (t < NB) ? binCounts[t] : 0;
    ts[t] = v;
    __syncthreads();
    for (int o = 1; o < 256; o <<= 1) {
        int u = (t >= o) ? ts[t - o] : 0;
        __syncthreads();
        ts[t] += u;
        __syncthreads();
    }
    const int excl = ts[t] - v;
    if (t <= NB) binOffs[t] = excl;     // binOffs[NB] = E
    if (t < NB) binCursor[t] = excl;
}

__global__ __launch_bounds__(256) void k_bin(const int* __restrict__ eidx,
                                             int* __restrict__ binCursor,
                                             unsigned int* __restrict__ binned, int E) {
    __shared__ int lh[256];
    __shared__ int lb[256];
    const int t = threadIdx.x;
    lh[t] = 0;
    __syncthreads();
    const int base = blockIdx.x * 2048;
    int bj[8], rj[8];
    unsigned int recj[8];
#pragma unroll
    for (int j = 0; j < 8; ++j) {
        const int e = base + j * 256 + t;
        bj[j] = -1;
        if (e < E) {
            const int s = eidx[e];
            const int d = eidx[E + e];
            bj[j] = d >> 8;
            recj[j] = ((unsigned)(d & 255) << 24) | (unsigned)s;
            rj[j] = atomicAdd(&lh[bj[j]], 1);
        }
    }
    __syncthreads();
    const int c = lh[t];
    if (c) lb[t] = atomicAdd(&binCursor[t], c);
    __syncthreads();
#pragma unroll
    for (int j = 0; j < 8; ++j) {
        if (bj[j] >= 0) binned[lb[bj[j]] + rj[j]] = recj[j];
    }
}

// K2d: one block per bin; per-node counts + offs via LDS scan, then place
// src ids with LDS cursors (zero global atomics; writes are L2-local).
__global__ __launch_bounds__(256) void k_place(const unsigned int* __restrict__ binned,
                                               const int* __restrict__ binOffs,
                                               int* __restrict__ offs,
                                               int* __restrict__ src_s,
                                               int N, int E) {
    __shared__ int cnt[256];
    __shared__ int ts[256];
    __shared__ int cur[256];
    const int b = blockIdx.x;
    const int t = threadIdx.x;
    const int node0 = b * 256;
    const int r0 = binOffs[b], r1 = binOffs[b + 1];
    cnt[t] = 0;
    __syncthreads();
    for (int i = r0 + t; i < r1; i += 256)
        atomicAdd(&cnt[binned[i] >> 24], 1);
    __syncthreads();
    const int v = cnt[t];
    ts[t] = v;
    __syncthreads();
    for (int o = 1; o < 256; o <<= 1) {
        int u = (t >= o) ? ts[t - o] : 0;
        __syncthreads();
        ts[t] += u;
        __syncthreads();
    }
    const int excl = r0 + ts[t] - v;
    if (node0 + t < N) offs[node0 + t] = excl;
    cur[t] = excl;
    __syncthreads();
    for (int i = r0 + t; i < r1; i += 256) {
        const unsigned int rec = binned[i];
        const int pos = atomicAdd(&cur[rec >> 24], 1);
        src_s[pos] = (int)(rec & 0xFFFFFFu);
    }
    if (b == 0 && t == 0) offs[N] = E;
}

// ---------------------------------------------------------------------------
// K4: fused attention + online softmax + aggregation. One wave per node.
// 8 edges/iter, 8-lane dots via v_dot2 (f16). xl[src] gathered ONLY when its
// softmax weight can contribute (w > 1e-12): contribution bound is
// w*|xl|/denom <= 1e-12 * |xl| (denom >= 1), below fp32 ulp of the result.
// ---------------------------------------------------------------------------
__global__ __launch_bounds__(256) void k_agg(const unsigned int* __restrict__ xlh,
                                             const unsigned int* __restrict__ embh,
                                             const int* __restrict__ src_s,
                                             const int* __restrict__ offs,
                                             const float* __restrict__ bias,
                                             float* __restrict__ out, int N) {
    const int node = (int)((blockIdx.x * (size_t)blockDim.x + threadIdx.x) >> 6);
    const int lane = threadIdx.x & 63;
    if (node >= N) return;
    const int g = lane >> 3;        // edge slot 0..7
    const int sl = lane & 7;        // sub-lane within 8-group
    const int s0 = offs[node], s1 = offs[node + 1];

    const uint4* erow = (const uint4*)(embh + (size_t)node * (C / 2));
    const uint4 e0 = erow[sl * 2], e1 = erow[sl * 2 + 1];

    // self-loop logit = ||emb[node]||^2 (8-lane reduce; same in every group)
    float p = 0.0f;
    p = dot2acc(e0.x, e0.x, p); p = dot2acc(e0.y, e0.y, p);
    p = dot2acc(e0.z, e0.z, p); p = dot2acc(e0.w, e0.w, p);
    p = dot2acc(e1.x, e1.x, p); p = dot2acc(e1.y, e1.y, p);
    p = dot2acc(e1.z, e1.z, p); p = dot2acc(e1.w, e1.w, p);
#pragma unroll
    for (int o = 4; o >= 1; o >>= 1) p += __shfl_xor(p, o);

    float m = p;        // running max (self included)
    float d = 1.0f;     // exp(self - m) = 1
    const unsigned int xw = xlh[(size_t)node * (C / 2) + lane];
    float2 acc = {h2f_lo(xw), h2f_hi(xw)};

    for (int base = s0; base < s1; base += 8) {
        int mys = -1;
        if (lane < 8 && base + lane < s1) mys = src_s[base + lane];
        const int sg = __shfl(mys, g);
        const int sa = (sg >= 0) ? sg : node;

        const uint4* vrow = (const uint4*)(embh + (size_t)sa * (C / 2));
        const uint4 v0 = vrow[sl * 2], v1 = vrow[sl * 2 + 1];
        float a = 0.0f;
        a = dot2acc(e0.x, v0.x, a); a = dot2acc(e0.y, v0.y, a);
        a = dot2acc(e0.z, v0.z, a); a = dot2acc(e0.w, v0.w, a);
        a = dot2acc(e1.x, v1.x, a); a = dot2acc(e1.y, v1.y, a);
        a = dot2acc(e1.z, v1.z, a); a = dot2acc(e1.w, v1.w, a);
#pragma unroll
        for (int o = 4; o >= 1; o >>= 1) a += __shfl_xor(a, o);
        if (sg < 0) a = -INFINITY;

        float ag[8]; int bg[8];
#pragma unroll
        for (int j = 0; j < 8; ++j) {
            ag[j] = __shfl(a, j * 8);
            bg[j] = __shfl(mys, j);
        }
        const float amax = fmaxf(fmaxf(fmaxf(ag[0], ag[1]), fmaxf(ag[2], ag[3])),
                                 fmaxf(fmaxf(ag[4], ag[5]), fmaxf(ag[6], ag[7])));
        if (amax > m) {                 // wave-uniform, rare
            const float cs = __expf(m - amax);
            d *= cs; acc.x *= cs; acc.y *= cs;
            m = amax;
        }
        float w[8];
#pragma unroll
        for (int j = 0; j < 8; ++j) {
            w[j] = __expf(ag[j] - m);
            d += w[j];
        }
#pragma unroll
        for (int j = 0; j < 8; ++j) {
            if (w[j] > 1e-12f) {        // wave-uniform (w broadcast)
                const unsigned int u = xlh[(size_t)bg[j] * (C / 2) + lane];
                acc.x = fmaf(w[j], h2f_lo(u), acc.x);
                acc.y = fmaf(w[j], h2f_hi(u), acc.y);
            }
        }
    }

    const float inv = 1.0f / (d + 1e-16f);
    const int c = lane * 2;
    float2 o2;
    o2.x = fmaf(acc.x, inv, bias[c]);
    o2.y = fmaf(acc.y, inv, bias[c + 1]);
    ((float2*)(out + (size_t)node * C))[lane] = o2;
}

// ---------------------------------------------------------------------------
// K5: BN stats — grid-stride float4; fixed channel quad per thread.
// ---------------------------------------------------------------------------
__global__ __launch_bounds__(256) void k_bnstats(const float* __restrict__ out,
                                                 float* __restrict__ ssum,
                                                 float* __restrict__ ssq, int N) {
    const int tid = threadIdx.x;
    const int total4 = N * (C / 4);
    const int stride = gridDim.x * 256;          // multiple of 32
    float4 s4 = {0, 0, 0, 0}, q4 = {0, 0, 0, 0};
    for (int i = blockIdx.x * 256 + tid; i < total4; i += stride) {
        float4 v = ((const float4*)out)[i];
        s4.x += v.x; s4.y += v.y; s4.z += v.z; s4.w += v.w;
        q4.x = fmaf(v.x, v.x, q4.x); q4.y = fmaf(v.y, v.y, q4.y);
        q4.z = fmaf(v.z, v.z, q4.z); q4.w = fmaf(v.w, v.w, q4.w);
    }
    __shared__ float4 lsum[256];
    __shared__ float4 lsq[256];
    lsum[tid] = s4; lsq[tid] = q4;
    __syncthreads();
    if (tid < 32) {
        float4 S = lsum[tid], Q = lsq[tid];
#pragma unroll
        for (int j = 1; j < 8; ++j) {
            float4 a = lsum[tid + 32 * j], b = lsq[tid + 32 * j];
            S.x += a.x; S.y += a.y; S.z += a.z; S.w += a.w;
            Q.x += b.x; Q.y += b.y; Q.z += b.z; Q.w += b.w;
        }
        const int c = tid * 4;
        atomicAdd(&ssum[c], S.x);     atomicAdd(&ssum[c + 1], S.y);
        atomicAdd(&ssum[c + 2], S.z); atomicAdd(&ssum[c + 3], S.w);
        atomicAdd(&ssq[c], Q.x);      atomicAdd(&ssq[c + 1], Q.y);
        atomicAdd(&ssq[c + 2], Q.z);  atomicAdd(&ssq[c + 3], Q.w);
    }
}

// ---------------------------------------------------------------------------
// K6: in-place BN apply (training-mode batch stats, biased var) + ReLU
// ---------------------------------------------------------------------------
__global__ __launch_bounds__(256) void k_bnapply(float* __restrict__ out,
                                                 const float* __restrict__ ssum,
                                                 const float* __restrict__ ssq,
                                                 const float* __restrict__ gamma,
                                                 const float* __restrict__ beta,
                                                 int N) {
    const int idx = blockIdx.x * blockDim.x + threadIdx.x;   // float4 index
    const int total = N * (C / 4);
    if (idx >= total) return;
    const int c = (idx * 4) & 127;
    float4 v = ((const float4*)out)[idx];
    const float invN = 1.0f / (float)N;
    float r[4] = {v.x, v.y, v.z, v.w};
#pragma unroll
    for (int j = 0; j < 4; ++j) {
        float mu = ssum[c + j] * invN;
        float var = fmaf(-mu, mu, ssq[c + j] * invN);
        var = fmaxf(var, 0.0f);
        float sc = gamma[c + j] / sqrtf(var + 1e-5f);
        float val = fmaf(r[j] - mu, sc, beta[c + j]);
        r[j] = fmaxf(val, 0.0f);
    }
    float4 o = {r[0], r[1], r[2], r[3]};
    ((float4*)out)[idx] = o;
}

// ---------------------------------------------------------------------------
extern "C" void kernel_launch(void* const* d_in, const int* in_sizes, int n_in,
                              void* d_out, int out_size, void* d_ws, size_t ws_size,
                              hipStream_t stream) {
    const float* x     = (const float*)d_in[0];
    const int*   eidx  = (const int*)d_in[1];   // [2][E]
    const float* emb   = (const float*)d_in[2];
    const float* W     = (const float*)d_in[3];
    const float* bias  = (const float*)d_in[4];
    const float* gamma = (const float*)d_in[5];
    const float* beta  = (const float*)d_in[6];
    const int N = in_sizes[0] / C;
    const int E = in_sizes[1] / 2;
    float* out = (float*)d_out;

    char* ws = (char*)d_ws;
    size_t off = 0;
    auto alloc = [&](size_t bytes) -> void* {
        void* p = ws + off;
        off = (off + bytes + 255) & ~(size_t)255;
        return p;
    };
    unsigned short* xlh  = (unsigned short*)alloc((size_t)N * C * 2);
    unsigned int*   embh = (unsigned int*)  alloc((size_t)N * C * 2);
    unsigned int*   wh   = (unsigned int*)  alloc((size_t)C * C * 2);
    int*   src_s    = (int*)  alloc((size_t)E * 4);
    unsigned int* binned = (unsigned int*)alloc((size_t)E * 4);
    int*   offs     = (int*)  alloc((size_t)(N + 1) * 4);
    int*   binOffs  = (int*)  alloc(257 * 4);
    int*   binCur   = (int*)  alloc(256 * 4);
    // contiguous zero-init region: binCounts + ssum + ssq
    char*  zbase    = (char*)alloc(0);
    int*   binCounts= (int*)  alloc(256 * 4);
    float* ssum     = (float*)alloc(C * 4);
    float* ssq      = (float*)alloc(C * 4);
    size_t zbytes   = (char*)ws + off - zbase;

    const int NB = (N + 255) / 256;              // 196 bins (<= 255)
    const int nEdgeBlocks = (E + 2047) / 2048;   // 391
    const int embTot8 = N * (C / 8);
    const int wTot8   = C * (C / 8);

    hipMemsetAsync(zbase, 0, zbytes, stream);

    k_cast   <<<(embTot8 + wTot8 + 255) / 256, 256, 0, stream>>>(
                 emb, embh, W, wh, embTot8, wTot8);
    k_gemm   <<<(N + 63) / 64,   256, 0, stream>>>(x, (const uint4*)wh, xlh, N);
    k_binhist<<<nEdgeBlocks,     256, 0, stream>>>(eidx, binCounts, E);
    k_binscan<<<1,               256, 0, stream>>>(binCounts, binOffs, binCur, NB);
    k_bin    <<<nEdgeBlocks,     256, 0, stream>>>(eidx, binCur, binned, E);
    k_place  <<<NB,              256, 0, stream>>>(binned, binOffs, offs, src_s, N, E);
    k_agg    <<<(int)(((size_t)N * 64 + 255) / 256), 256, 0, stream>>>(
                 (const unsigned int*)xlh, embh, src_s, offs, bias, out, N);
    k_bnstats<<<256,             256, 0, stream>>>(out, ssum, ssq, N);
    k_bnapply<<<(N * (C / 4) + 255) / 256, 256, 0, stream>>>(out, ssum, ssq, gamma, beta, N);
}